// Round 6
// baseline (606.800 us; speedup 1.0000x reference)
//
#include <hip/hip_runtime.h>

#define Bdim 2
#define Tdim 2048
#define Cdim 2048
#define Hn 16
#define Dh 128
#define NKB 16   // Cdim/128 k-blocks per row

typedef float f32x4 __attribute__((ext_vector_type(4)));
typedef short s16x8 __attribute__((ext_vector_type(8)));

// async global->LDS, 16B per lane, linear dest (base + lane*16)
#define GL16(g, l) __builtin_amdgcn_global_load_lds( \
    (const __attribute__((address_space(1))) unsigned int*)(g), \
    (__attribute__((address_space(3))) unsigned int*)(l), 16, 0, 0)

// ---------- numerics helpers ----------

// fp32 -> float8_e5m2 (RNE, subnormals, inf past 61440) -> fp32. Matches ml_dtypes.
__device__ __forceinline__ float q8_e5m2(float x) {
    unsigned int u = __float_as_uint(x);
    unsigned int sign = u & 0x80000000u;
    float ax = __uint_as_float(u & 0x7fffffffu);
    float r;
    if (ax < 6.103515625e-05f) {              // subnormal range: grid 2^-16
        r = rintf(ax * 65536.0f) * (1.0f / 65536.0f);
    } else if (ax >= 61440.0f) {
        r = __uint_as_float(0x7f800000u);
    } else {
        unsigned int m = __float_as_uint(ax);
        unsigned int rem  = m & 0x001FFFFFu;
        unsigned int keep = m & 0xFFE00000u;
        unsigned int lsb  = (m >> 21) & 1u;
        if (rem > 0x00100000u || (rem == 0x00100000u && lsb)) keep += 0x00200000u;
        r = __uint_as_float(keep);
    }
    return __uint_as_float(__float_as_uint(r) | sign);
}

__device__ __forceinline__ unsigned short f2bf(float f) {
    unsigned int u = __float_as_uint(f);
    u += 0x7fffu + ((u >> 16) & 1u);
    return (unsigned short)(u >> 16);
}
__device__ __forceinline__ float bf2f(unsigned short h) {
    return __uint_as_float((unsigned int)h << 16);
}
__device__ __forceinline__ float exp2_fast(float x) {
    float r; asm volatile("v_exp_f32 %0, %1" : "=v"(r) : "v"(x)); return r;
}

// ---------- act quant: per-128 block. out = bf16(q8(x/s)) [EXACT] + scale ----------
__global__ __launch_bounds__(256) void act_quant_q8_k(const float* __restrict__ in,
                                                      unsigned short* __restrict__ q,
                                                      float* __restrict__ S, int n128) {
    int wid = (int)((blockIdx.x * 256u + threadIdx.x) >> 6);
    int lane = threadIdx.x & 63;
    if (wid >= n128) return;
    const float* p = in + (size_t)wid * 128;
    float a = p[lane], b = p[lane + 64];
    float m = fmaxf(fabsf(a), fabsf(b));
#pragma unroll
    for (int o = 32; o; o >>= 1) m = fmaxf(m, __shfl_xor(m, o));
    float s = fmaxf(m / 57344.0f, 1e-12f);
    unsigned short* qp = q + (size_t)wid * 128;
    qp[lane]      = f2bf(q8_e5m2(a / s));
    qp[lane + 64] = f2bf(q8_e5m2(b / s));
    if (lane == 0) S[wid] = s;
}

// ---------- weight quant: out = bf16(q8(w)) [EXACT, scale in GEMM epilogue] ----------
__global__ __launch_bounds__(256) void w_quant_k(const float* __restrict__ w,
                                                 unsigned short* __restrict__ out, int n) {
    int i = (blockIdx.x * 256 + threadIdx.x) * 4;
    if (i >= n) return;
    float4 t = *(const float4*)(w + i);
    out[i + 0] = f2bf(q8_e5m2(t.x));
    out[i + 1] = f2bf(q8_e5m2(t.y));
    out[i + 2] = f2bf(q8_e5m2(t.z));
    out[i + 3] = f2bf(q8_e5m2(t.w));
}

// ---------- GEMM (m97 structure): C = (Aq*Sa) @ Bq^T * Sb ----------
// Linear LDS [128 rows][4 chunks of 16B], slot = row*4 + (chunk ^ ((row>>1)&3)).
// Staged via global_load_lds (source pre-swizzled), read via swizzled ds_read_b128.
template<int OUTF32>
__global__ __launch_bounds__(256) void gemm_k(const unsigned short* __restrict__ Aq,
                                              const float* __restrict__ Sa,
                                              const unsigned short* __restrict__ Bq,
                                              const float* __restrict__ Sb,
                                              unsigned short* __restrict__ Oh,
                                              unsigned short* __restrict__ Ol,
                                              float* __restrict__ Of,
                                              int M, int N, int K) {
    __shared__ unsigned short As[128 * 32];
    __shared__ unsigned short Bs[128 * 32];
    int tid = threadIdx.x;
    int lane = tid & 63, wid = tid >> 6;
    int wr = wid >> 1, wc = wid & 1;
    int bm = blockIdx.y * 128, bn = blockIdx.x * 128;

    f32x4 acc[4][4], accp[4][4];
#pragma unroll
    for (int i = 0; i < 4; ++i)
#pragma unroll
        for (int j = 0; j < 4; ++j) {
            acc[i][j] = (f32x4){0.f, 0.f, 0.f, 0.f};
            accp[i][j] = (f32x4){0.f, 0.f, 0.f, 0.f};
        }

    const int frow = lane & 15;
    const int gq   = lane >> 4;
    const int rbase = gq * 4;
    const int nkb = K >> 7;

    // staging coords: wave wid covers rows wid*32 .. wid*32+31 (2 gloads x 16 rows)
    int srA = (lane >> 2);              // row within 16-row group
    int sch = (lane & 3);

    const int nstep = K >> 5;
    for (int step = 0; step < nstep; ++step) {
        int k0 = step << 5;
        __syncthreads();   // all reads of previous tile done
#pragma unroll
        for (int i = 0; i < 2; ++i) {
            int row = wid * 32 + i * 16 + srA;
            int ch = sch ^ ((row >> 1) & 3);
            GL16(Aq + (size_t)(bm + row) * K + k0 + ch * 8, As + (wid * 128 + i * 64) * 8);
            GL16(Bq + (size_t)(bn + row) * K + k0 + ch * 8, Bs + (wid * 128 + i * 64) * 8);
        }
        __syncthreads();   // vmcnt drained by barrier -> tile visible
        s16x8 af[4], bfr[4];
#pragma unroll
        for (int m = 0; m < 4; ++m) {
            int row = wr * 64 + m * 16 + frow;
            int slot = row * 4 + (gq ^ ((row >> 1) & 3));
            af[m] = *(const s16x8*)(const void*)(As + slot * 8);
        }
#pragma unroll
        for (int n = 0; n < 4; ++n) {
            int row = wc * 64 + n * 16 + frow;
            int slot = row * 4 + (gq ^ ((row >> 1) & 3));
            bfr[n] = *(const s16x8*)(const void*)(Bs + slot * 8);
        }
#pragma unroll
        for (int m = 0; m < 4; ++m)
#pragma unroll
            for (int n = 0; n < 4; ++n)
                accp[m][n] = __builtin_amdgcn_mfma_f32_16x16x32_bf16(af[m], bfr[n], accp[m][n], 0, 0, 0);

        if ((step & 3) == 3) {   // fold per 128-K block with per-row act scale
            int kb = step >> 2;
#pragma unroll
            for (int m = 0; m < 4; ++m) {
                int rowb = bm + wr * 64 + m * 16 + rbase;
                float s0 = Sa[(size_t)(rowb + 0) * nkb + kb];
                float s1 = Sa[(size_t)(rowb + 1) * nkb + kb];
                float s2 = Sa[(size_t)(rowb + 2) * nkb + kb];
                float s3 = Sa[(size_t)(rowb + 3) * nkb + kb];
#pragma unroll
                for (int n = 0; n < 4; ++n) {
                    acc[m][n][0] += s0 * accp[m][n][0];
                    acc[m][n][1] += s1 * accp[m][n][1];
                    acc[m][n][2] += s2 * accp[m][n][2];
                    acc[m][n][3] += s3 * accp[m][n][3];
                    accp[m][n] = (f32x4){0.f, 0.f, 0.f, 0.f};
                }
            }
        }
    }

    int row0 = bm + wr * 64, col0 = bn + wc * 64;
    int cl = lane & 15;
#pragma unroll
    for (int n = 0; n < 4; ++n) {
        float sb = Sb[(col0 + n * 16) >> 7];
#pragma unroll
        for (int m = 0; m < 4; ++m)
#pragma unroll
            for (int r = 0; r < 4; ++r) {
                int row = row0 + m * 16 + rbase + r;
                int col = col0 + n * 16 + cl;
                float val = acc[m][n][r] * sb;
                if (OUTF32) {
                    Of[(size_t)row * N + col] = val;
                } else {
                    unsigned short hi = f2bf(val);
                    Oh[(size_t)row * N + col] = hi;
                    Ol[(size_t)row * N + col] = f2bf(val - bf2f(hi));
                }
            }
    }
}

// ---------- V transpose: [B,T,H*D] plane -> [B,H,D,T] plane ----------
__global__ __launch_bounds__(256) void vtrans_k(const unsigned short* __restrict__ in_p,
                                                unsigned short* __restrict__ out_p) {
    __shared__ unsigned short tile[64 * 72];
    int t0 = blockIdx.x * 64, d0 = blockIdx.y * 64;
    int b = blockIdx.z >> 4, h = blockIdx.z & 15;
    int tid = threadIdx.x;
    int r = tid >> 3, c8 = (tid & 7) * 8;
    const unsigned short* in = in_p + ((size_t)b * Tdim + t0) * Cdim + h * Dh + d0;
    unsigned short* out = out_p + (((size_t)b * Hn + h) * Dh + d0) * Tdim + t0;
#pragma unroll
    for (int rr = r; rr < 64; rr += 32) {
        int cs = c8 ^ ((rr >> 3) << 3);
        *(int4*)(void*)(tile + rr * 72 + cs) =
            *(const int4*)(const void*)(in + (size_t)rr * Cdim + c8);
    }
    __syncthreads();
#pragma unroll
    for (int dr = r; dr < 64; dr += 32) {
        s16x8 v;
#pragma unroll
        for (int j = 0; j < 8; ++j) {
            int row = c8 + j;
            int col = dr ^ ((row >> 3) << 3);
            v[j] = (short)tile[row * 72 + col];
        }
        *(s16x8*)(void*)(out + (size_t)dr * Tdim + c8) = v;
    }
}

// ---------- flash attention: LDS-staged K/V (gload_lds, dbuf), XCD affinity ----------
#define QB 64
#define KB 32
#define PLD 40   // Ps row stride

__device__ __forceinline__ void stage_tile(const unsigned short* Khp, const unsigned short* Klp,
                                           const unsigned short* Vhp, const unsigned short* Vlp,
                                           unsigned short* Kbh, unsigned short* Kbl,
                                           unsigned short* Vbh, unsigned short* Vbl,
                                           int j0, int wid, int lane) {
#pragma unroll
    for (int i2 = 0; i2 < 2; ++i2) {
        int s = (wid * 2 + i2) * 64 + lane;
        int r = s >> 4, ch = (s & 15) ^ (r & 7);
        GL16(Khp + (size_t)(j0 + r) * Cdim + ch * 8, Kbh + s * 8);
        GL16(Klp + (size_t)(j0 + r) * Cdim + ch * 8, Kbl + s * 8);
        int d = s >> 2, cv = (s & 3) ^ ((d >> 1) & 3);
        GL16(Vhp + (size_t)d * Tdim + j0 + cv * 8, Vbh + s * 8);
        GL16(Vlp + (size_t)d * Tdim + j0 + cv * 8, Vbl + s * 8);
    }
}

__global__ __launch_bounds__(256, 2) void attn_k(const unsigned short* __restrict__ Qh,
                                                 const unsigned short* __restrict__ Ql,
                                                 const unsigned short* __restrict__ Kh,
                                                 const unsigned short* __restrict__ Kl,
                                                 const unsigned short* __restrict__ Vth,
                                                 const unsigned short* __restrict__ Vtl,
                                                 unsigned short* __restrict__ ctxq,
                                                 float* __restrict__ Sc) {
    __shared__ unsigned short Kbh[2][4096], Kbl[2][4096];
    __shared__ unsigned short Vbh[2][4096], Vbl[2][4096];
    __shared__ unsigned short Psh[4][16 * PLD], Psl[4][16 * PLD];

    int tid = threadIdx.x, lane = tid & 63, wid = tid >> 6;
    int g = blockIdx.x;
    int xcd = g & 7, sl = g >> 3;
    int combo = xcd + 8 * (sl >> 4);     // 0..31
    int pr = sl & 15;
    int b = combo >> 4, h = combo & 15;

    const size_t qkbase = (size_t)b * Tdim * Cdim + (size_t)h * Dh;
    const size_t vbase  = ((size_t)b * Hn + h) * (size_t)Dh * Tdim;
    const unsigned short* Qhp = Qh + qkbase;
    const unsigned short* Qlp = Ql + qkbase;
    const unsigned short* Khp = Kh + qkbase;
    const unsigned short* Klp = Kl + qkbase;
    const unsigned short* Vhp = Vth + vbase;
    const unsigned short* Vlp = Vtl + vbase;

    int cl = lane & 15;
    int gq = lane >> 4;
    int fk = gq * 8;
    int rb4 = gq * 4;
    // log2-domain score scale: 1/sqrt(128) * log2(e)
    const float qscl2 = 0.088388347648318447f * 1.4426950408889634f;

    for (int pass = 0; pass < 2; ++pass) {
        int qt = pass ? (31 - pr) : pr;
        int qrow_lo = qt * QB + wid * 16;
        int myrow = qrow_lo + cl;
        int qmax_w = qrow_lo + 15;

        s16x8 qfh[4], qfl[4];
#pragma unroll
        for (int c = 0; c < 4; ++c) {
            qfh[c] = *(const s16x8*)(const void*)(Qhp + (size_t)myrow * Cdim + c * 32 + fk);
            qfl[c] = *(const s16x8*)(const void*)(Qlp + (size_t)myrow * Cdim + c * 32 + fk);
        }

        f32x4 acc[8];
#pragma unroll
        for (int n = 0; n < 8; ++n) acc[n] = (f32x4){0.f, 0.f, 0.f, 0.f};
        float mrun[4], lrun[4];
#pragma unroll
        for (int r = 0; r < 4; ++r) { mrun[r] = -__builtin_inff(); lrun[r] = 0.f; }

        int ntile = 2 * qt + 2;
        int cur = 0;

        stage_tile(Khp, Klp, Vhp, Vlp, Kbh[0], Kbl[0], Vbh[0], Vbl[0], 0, wid, lane);
        __syncthreads();

        for (int t = 0; t < ntile; ++t) {
            int j0 = t * KB;
            if (t + 1 < ntile)
                stage_tile(Khp, Klp, Vhp, Vlp, Kbh[cur ^ 1], Kbl[cur ^ 1],
                           Vbh[cur ^ 1], Vbl[cur ^ 1], j0 + KB, wid, lane);
            if (j0 <= qmax_w) {
                const unsigned short* kbh = Kbh[cur];
                const unsigned short* kbl = Kbl[cur];
                const unsigned short* vbh = Vbh[cur];
                const unsigned short* vbl = Vbl[cur];
                // ---- QK^T from LDS ----
                f32x4 sf[2];
#pragma unroll
                for (int st = 0; st < 2; ++st) {
                    int rr = st * 16 + cl;
                    f32x4 sa = (f32x4){0.f, 0.f, 0.f, 0.f};
#pragma unroll
                    for (int c = 0; c < 4; ++c) {
                        int slot = rr * 16 + ((c * 4 + gq) ^ (rr & 7));
                        s16x8 kfh = *(const s16x8*)(const void*)(kbh + slot * 8);
                        s16x8 kfl = *(const s16x8*)(const void*)(kbl + slot * 8);
                        sa = __builtin_amdgcn_mfma_f32_16x16x32_bf16(qfh[c], kfh, sa, 0, 0, 0);
                        sa = __builtin_amdgcn_mfma_f32_16x16x32_bf16(qfh[c], kfl, sa, 0, 0, 0);
                        sa = __builtin_amdgcn_mfma_f32_16x16x32_bf16(qfl[c], kfh, sa, 0, 0, 0);
                    }
                    sf[st] = sa;
                }
                // ---- log2-scale + causal mask ----
#pragma unroll
                for (int st = 0; st < 2; ++st) {
                    int key = j0 + st * 16 + cl;
#pragma unroll
                    for (int r = 0; r < 4; ++r) {
                        int qr = qrow_lo + rb4 + r;
                        float sv = sf[st][r] * qscl2;
                        sf[st][r] = (key <= qr) ? sv : -__builtin_inff();
                    }
                }
                // ---- online softmax (log2 domain) with defer-max ----
                float tm[4];
                bool need = false;
#pragma unroll
                for (int r = 0; r < 4; ++r) {
                    float t2 = fmaxf(sf[0][r], sf[1][r]);
#pragma unroll
                    for (int o = 8; o; o >>= 1) t2 = fmaxf(t2, __shfl_xor(t2, o));
                    tm[r] = t2;
                    need = need || (t2 > mrun[r] + 8.f);
                }
                if (__any(need)) {
                    float corr[4];
#pragma unroll
                    for (int r = 0; r < 4; ++r) {
                        float mn = fmaxf(mrun[r], tm[r]);
                        corr[r] = exp2_fast(mrun[r] - mn);
                        mrun[r] = mn;
                        lrun[r] *= corr[r];
                    }
#pragma unroll
                    for (int n = 0; n < 8; ++n)
#pragma unroll
                        for (int r = 0; r < 4; ++r) acc[n][r] *= corr[r];
                }
                float p0[4], p1[4];
#pragma unroll
                for (int r = 0; r < 4; ++r) {
                    p0[r] = exp2_fast(sf[0][r] - mrun[r]);
                    p1[r] = exp2_fast(sf[1][r] - mrun[r]);
                    float rs = p0[r] + p1[r];
#pragma unroll
                    for (int o = 8; o; o >>= 1) rs += __shfl_xor(rs, o);
                    lrun[r] += rs;
                }
                // ---- P bounce through per-wave LDS ----
                unsigned short* psh = &Psh[wid][0];
                unsigned short* psl = &Psl[wid][0];
#pragma unroll
                for (int r = 0; r < 4; ++r) {
                    unsigned short h0 = f2bf(p0[r]);
                    unsigned short h1 = f2bf(p1[r]);
                    psh[(rb4 + r) * PLD + cl]      = h0;
                    psl[(rb4 + r) * PLD + cl]      = f2bf(p0[r] - bf2f(h0));
                    psh[(rb4 + r) * PLD + 16 + cl] = h1;
                    psl[(rb4 + r) * PLD + 16 + cl] = f2bf(p1[r] - bf2f(h1));
                }
                s16x8 pfh = *(const s16x8*)(const void*)(psh + cl * PLD + fk);
                s16x8 pfl = *(const s16x8*)(const void*)(psl + cl * PLD + fk);
                // ---- PV from LDS ----
#pragma unroll
                for (int n = 0; n < 8; ++n) {
                    int d = n * 16 + cl;
                    int slot = d * 4 + (gq ^ ((d >> 1) & 3));
                    s16x8 vfh = *(const s16x8*)(const void*)(vbh + slot * 8);
                    s16x8 vfl = *(const s16x8*)(const void*)(vbl + slot * 8);
                    acc[n] = __builtin_amdgcn_mfma_f32_16x16x32_bf16(pfh, vfh, acc[n], 0, 0, 0);
                    acc[n] = __builtin_amdgcn_mfma_f32_16x16x32_bf16(pfh, vfl, acc[n], 0, 0, 0);
                    acc[n] = __builtin_amdgcn_mfma_f32_16x16x32_bf16(pfl, vfh, acc[n], 0, 0, 0);
                }
            }
            __syncthreads();
            cur ^= 1;
        }
        // ---- epilogue: normalize + fused e5m2 block quant ----
        unsigned short* cq = ctxq + qkbase;
#pragma unroll
        for (int r = 0; r < 4; ++r) {
            int trow = qrow_lo + rb4 + r;
            float inv = 1.0f / lrun[r];
            float vals[8];
            float am = 0.f;
#pragma unroll
            for (int n = 0; n < 8; ++n) {
                vals[n] = acc[n][r] * inv;
                am = fmaxf(am, fabsf(vals[n]));
            }
#pragma unroll
            for (int o = 8; o; o >>= 1) am = fmaxf(am, __shfl_xor(am, o));
            float s = fmaxf(am / 57344.0f, 1e-12f);
#pragma unroll
            for (int n = 0; n < 8; ++n)
                cq[(size_t)trow * Cdim + n * 16 + cl] = f2bf(q8_e5m2(vals[n] / s));
            if (cl == 0) Sc[((size_t)b * Tdim + trow) * NKB + h] = s;
        }
    }
}

// ---------- launch ----------
extern "C" void kernel_launch(void* const* d_in, const int* in_sizes, int n_in,
                              void* d_out, int out_size, void* d_ws, size_t ws_size,
                              hipStream_t stream) {
    const float* x  = (const float*)d_in[0];
    const float* wq = (const float*)d_in[2];
    const float* wk = (const float*)d_in[3];
    const float* wv = (const float*)d_in[4];
    const float* wo = (const float*)d_in[5];
    const float* sq = (const float*)d_in[6];
    const float* sk = (const float*)d_in[7];
    const float* sv = (const float*)d_in[8];
    const float* so = (const float*)d_in[9];

    const size_t MB = 1ull << 20;
    char* ws = (char*)d_ws;
    unsigned short* xq  = (unsigned short*)(ws);                       // 0..16: xq -> vth
    unsigned short* vth = (unsigned short*)(ws);
    float*          Sx  = (float*)(ws + 16 * MB);
    float*          Scx = (float*)(ws + (16 * MB + 256 * 1024));
    unsigned short* wdq = (unsigned short*)(ws + (16 * MB + 512 * 1024));
    unsigned short* qh  = (unsigned short*)(ws + (24 * MB + 512 * 1024));
    unsigned short* ql  = (unsigned short*)(ws + (40 * MB + 512 * 1024));
    unsigned short* kh  = (unsigned short*)(ws + (56 * MB + 512 * 1024));
    unsigned short* kl  = (unsigned short*)(ws + (72 * MB + 512 * 1024));
    unsigned short* vh  = (unsigned short*)(ws + (88 * MB + 512 * 1024));  // vh -> vtl
    unsigned short* vtl = (unsigned short*)(ws + (88 * MB + 512 * 1024));
    unsigned short* vl  = (unsigned short*)(ws + (104 * MB + 512 * 1024)); // vl -> cq
    unsigned short* cq  = (unsigned short*)(ws + (104 * MB + 512 * 1024));

    const int n128 = Bdim * Tdim * Cdim / 128;  // 65536
    const int wn = Cdim * Cdim;
    const int Mr = Bdim * Tdim;

    act_quant_q8_k<<<n128 / 4, 256, 0, stream>>>(x, xq, Sx, n128);

    dim3 gg(Cdim / 128, Mr / 128);
    w_quant_k<<<wn / 1024, 256, 0, stream>>>(wq, wdq, wn);
    gemm_k<0><<<gg, 256, 0, stream>>>(xq, Sx, wdq, sq, qh, ql, nullptr, Mr, Cdim, Cdim);
    w_quant_k<<<wn / 1024, 256, 0, stream>>>(wk, wdq, wn);
    gemm_k<0><<<gg, 256, 0, stream>>>(xq, Sx, wdq, sk, kh, kl, nullptr, Mr, Cdim, Cdim);
    w_quant_k<<<wn / 1024, 256, 0, stream>>>(wv, wdq, wn);
    gemm_k<0><<<gg, 256, 0, stream>>>(xq, Sx, wdq, sv, vh, vl, nullptr, Mr, Cdim, Cdim);

    dim3 tg(Tdim / 64, Dh / 64, Bdim * Hn);
    vtrans_k<<<tg, 256, 0, stream>>>(vh, vth);
    vtrans_k<<<tg, 256, 0, stream>>>(vl, vtl);

    attn_k<<<512, 256, 0, stream>>>(qh, ql, kh, kl, vth, vtl, cq, Scx);

    w_quant_k<<<wn / 1024, 256, 0, stream>>>(wo, wdq, wn);
    gemm_k<1><<<gg, 256, 0, stream>>>(cq, Scx, wdq, so, nullptr, nullptr, (float*)d_out, Mr, Cdim, Cdim);
}

// Round 7
// 544.502 us; speedup vs baseline: 1.1144x; 1.1144x over previous
//
#include <hip/hip_runtime.h>

#define Bdim 2
#define Tdim 2048
#define Cdim 2048
#define Hn 16
#define Dh 128
#define NKB 16   // Cdim/128 k-blocks per row

typedef float f32x4 __attribute__((ext_vector_type(4)));
typedef short s16x8 __attribute__((ext_vector_type(8)));

// async global->LDS, 16B per lane, linear dest (base + lane*16)
#define GL16(g, l) __builtin_amdgcn_global_load_lds( \
    (const __attribute__((address_space(1))) unsigned int*)(g), \
    (__attribute__((address_space(3))) unsigned int*)(l), 16, 0, 0)

// ---------- numerics helpers ----------

// fp32 -> float8_e5m2 (RNE, subnormals, inf past 61440) -> fp32. Matches ml_dtypes.
__device__ __forceinline__ float q8_e5m2(float x) {
    unsigned int u = __float_as_uint(x);
    unsigned int sign = u & 0x80000000u;
    float ax = __uint_as_float(u & 0x7fffffffu);
    float r;
    if (ax < 6.103515625e-05f) {              // subnormal range: grid 2^-16
        r = rintf(ax * 65536.0f) * (1.0f / 65536.0f);
    } else if (ax >= 61440.0f) {
        r = __uint_as_float(0x7f800000u);
    } else {
        unsigned int m = __float_as_uint(ax);
        unsigned int rem  = m & 0x001FFFFFu;
        unsigned int keep = m & 0xFFE00000u;
        unsigned int lsb  = (m >> 21) & 1u;
        if (rem > 0x00100000u || (rem == 0x00100000u && lsb)) keep += 0x00200000u;
        r = __uint_as_float(keep);
    }
    return __uint_as_float(__float_as_uint(r) | sign);
}

__device__ __forceinline__ unsigned short f2bf(float f) {
    unsigned int u = __float_as_uint(f);
    u += 0x7fffu + ((u >> 16) & 1u);
    return (unsigned short)(u >> 16);
}
__device__ __forceinline__ float bf2f(unsigned short h) {
    return __uint_as_float((unsigned int)h << 16);
}
__device__ __forceinline__ float exp2_fast(float x) {
    float r; asm volatile("v_exp_f32 %0, %1" : "=v"(r) : "v"(x)); return r;
}

// ---------- act quant: per-128 block. out = bf16(q8(x/s)) [EXACT] + scale ----------
__global__ __launch_bounds__(256) void act_quant_q8_k(const float* __restrict__ in,
                                                      unsigned short* __restrict__ q,
                                                      float* __restrict__ S, int n128) {
    int wid = (int)((blockIdx.x * 256u + threadIdx.x) >> 6);
    int lane = threadIdx.x & 63;
    if (wid >= n128) return;
    const float* p = in + (size_t)wid * 128;
    float a = p[lane], b = p[lane + 64];
    float m = fmaxf(fabsf(a), fabsf(b));
#pragma unroll
    for (int o = 32; o; o >>= 1) m = fmaxf(m, __shfl_xor(m, o));
    float s = fmaxf(m / 57344.0f, 1e-12f);
    unsigned short* qp = q + (size_t)wid * 128;
    qp[lane]      = f2bf(q8_e5m2(a / s));
    qp[lane + 64] = f2bf(q8_e5m2(b / s));
    if (lane == 0) S[wid] = s;
}

// ---------- weight quant: out = bf16(q8(w)) [EXACT, scale in GEMM epilogue] ----------
__global__ __launch_bounds__(256) void w_quant_k(const float* __restrict__ w,
                                                 unsigned short* __restrict__ out, int n) {
    int i = (blockIdx.x * 256 + threadIdx.x) * 4;
    if (i >= n) return;
    float4 t = *(const float4*)(w + i);
    out[i + 0] = f2bf(q8_e5m2(t.x));
    out[i + 1] = f2bf(q8_e5m2(t.y));
    out[i + 2] = f2bf(q8_e5m2(t.z));
    out[i + 3] = f2bf(q8_e5m2(t.w));
}

// ---------- GEMM: 2-phase dbuf gload_lds, counted vmcnt(4), Sa in LDS ----------
// Linear LDS slot s (16B) holds global (row = s>>2, chunk = (s&3)^((row>>1)&3)).
template<int OUTF32>
__global__ __launch_bounds__(256) void gemm_k(const unsigned short* __restrict__ Aq,
                                              const float* __restrict__ Sa,
                                              const unsigned short* __restrict__ Bq,
                                              const float* __restrict__ Sb,
                                              unsigned short* __restrict__ Oh,
                                              unsigned short* __restrict__ Ol,
                                              float* __restrict__ Of,
                                              int M, int N, int K) {
    __shared__ unsigned short As[2][4096];   // 8KB per buf
    __shared__ unsigned short Bs[2][4096];
    __shared__ float SaL[128 * NKB];         // per-row,k-block act scales (8KB)
    int tid = threadIdx.x;
    int lane = tid & 63, wid = tid >> 6;
    int wr = wid >> 1, wc = wid & 1;
    int bm = blockIdx.y * 128, bn = blockIdx.x * 128;

    f32x4 acc[4][4], accp[4][4];
#pragma unroll
    for (int i = 0; i < 4; ++i)
#pragma unroll
        for (int j = 0; j < 4; ++j) {
            acc[i][j] = (f32x4){0.f, 0.f, 0.f, 0.f};
            accp[i][j] = (f32x4){0.f, 0.f, 0.f, 0.f};
        }

    const int frow = lane & 15;
    const int gq   = lane >> 4;
    const int rbase = gq * 4;
    const int nkb = K >> 7;

    // staging coords
    int srA = (lane >> 2);
    int sch = (lane & 3);

    // prologue: Sa block -> LDS
    for (int i = tid; i < 128 * NKB; i += 256) {
        int row = i >> 4, kb = i & 15;
        SaL[i] = Sa[(size_t)(bm + row) * nkb + kb];
    }

#define STAGE_G(buf, step) do { \
        int k0s = (step) << 5; \
        _Pragma("unroll") \
        for (int i = 0; i < 2; ++i) { \
            int row = wid * 32 + i * 16 + srA; \
            int ch = sch ^ ((row >> 1) & 3); \
            GL16(Aq + (size_t)(bm + row) * K + k0s + ch * 8, As[buf] + (wid * 128 + i * 64) * 8); \
            GL16(Bq + (size_t)(bn + row) * K + k0s + ch * 8, Bs[buf] + (wid * 128 + i * 64) * 8); \
        } \
    } while (0)

    STAGE_G(0, 0);
    __syncthreads();   // drain prologue stage + Sa writes

    const int nstep = K >> 5;   // 64
    for (int step = 0; step < nstep; ++step) {
        int cur = step & 1;
        if (step + 1 < nstep) {
            STAGE_G(cur ^ 1, step + 1);                     // issue early; stays in flight
            asm volatile("s_waitcnt vmcnt(4)" ::: "memory"); // retire cur's 4, keep next's 4
        } else {
            asm volatile("s_waitcnt vmcnt(0)" ::: "memory");
        }
        __builtin_amdgcn_s_barrier();                        // cur visible chip-wide

        s16x8 af[4], bfr[4];
#pragma unroll
        for (int m = 0; m < 4; ++m) {
            int row = wr * 64 + m * 16 + frow;
            int slot = row * 4 + (gq ^ ((row >> 1) & 3));
            af[m] = *(const s16x8*)(const void*)(As[cur] + slot * 8);
        }
#pragma unroll
        for (int n = 0; n < 4; ++n) {
            int row = wc * 64 + n * 16 + frow;
            int slot = row * 4 + (gq ^ ((row >> 1) & 3));
            bfr[n] = *(const s16x8*)(const void*)(Bs[cur] + slot * 8);
        }
#pragma unroll
        for (int m = 0; m < 4; ++m)
#pragma unroll
            for (int n = 0; n < 4; ++n)
                accp[m][n] = __builtin_amdgcn_mfma_f32_16x16x32_bf16(af[m], bfr[n], accp[m][n], 0, 0, 0);

        if ((step & 3) == 3) {   // fold per 128-K block with per-row act scale (LDS)
            int kb = step >> 2;
#pragma unroll
            for (int m = 0; m < 4; ++m) {
                int rl = wr * 64 + m * 16 + rbase;
                float s0 = SaL[(rl + 0) * 16 + kb];
                float s1 = SaL[(rl + 1) * 16 + kb];
                float s2 = SaL[(rl + 2) * 16 + kb];
                float s3 = SaL[(rl + 3) * 16 + kb];
#pragma unroll
                for (int n = 0; n < 4; ++n) {
                    acc[m][n][0] += s0 * accp[m][n][0];
                    acc[m][n][1] += s1 * accp[m][n][1];
                    acc[m][n][2] += s2 * accp[m][n][2];
                    acc[m][n][3] += s3 * accp[m][n][3];
                    accp[m][n] = (f32x4){0.f, 0.f, 0.f, 0.f};
                }
            }
        }
        __builtin_amdgcn_s_barrier();   // all reads of cur done -> next stage may overwrite
    }
#undef STAGE_G

    int row0 = bm + wr * 64, col0 = bn + wc * 64;
    int cl = lane & 15;
#pragma unroll
    for (int n = 0; n < 4; ++n) {
        float sb = Sb[(col0 + n * 16) >> 7];
#pragma unroll
        for (int m = 0; m < 4; ++m)
#pragma unroll
            for (int r = 0; r < 4; ++r) {
                int row = row0 + m * 16 + rbase + r;
                int col = col0 + n * 16 + cl;
                float val = acc[m][n][r] * sb;
                if (OUTF32) {
                    Of[(size_t)row * N + col] = val;
                } else {
                    unsigned short hi = f2bf(val);
                    Oh[(size_t)row * N + col] = hi;
                    Ol[(size_t)row * N + col] = f2bf(val - bf2f(hi));
                }
            }
    }
}

// ---------- V transpose: [B,T,H*D] plane -> [B,H,D,T] plane ----------
__global__ __launch_bounds__(256) void vtrans_k(const unsigned short* __restrict__ in_p,
                                                unsigned short* __restrict__ out_p) {
    __shared__ unsigned short tile[64 * 72];
    int t0 = blockIdx.x * 64, d0 = blockIdx.y * 64;
    int b = blockIdx.z >> 4, h = blockIdx.z & 15;
    int tid = threadIdx.x;
    int r = tid >> 3, c8 = (tid & 7) * 8;
    const unsigned short* in = in_p + ((size_t)b * Tdim + t0) * Cdim + h * Dh + d0;
    unsigned short* out = out_p + (((size_t)b * Hn + h) * Dh + d0) * Tdim + t0;
#pragma unroll
    for (int rr = r; rr < 64; rr += 32) {
        int cs = c8 ^ ((rr >> 3) << 3);
        *(int4*)(void*)(tile + rr * 72 + cs) =
            *(const int4*)(const void*)(in + (size_t)rr * Cdim + c8);
    }
    __syncthreads();
#pragma unroll
    for (int dr = r; dr < 64; dr += 32) {
        s16x8 v;
#pragma unroll
        for (int j = 0; j < 8; ++j) {
            int row = c8 + j;
            int col = dr ^ ((row >> 3) << 3);
            v[j] = (short)tile[row * 72 + col];
        }
        *(s16x8*)(void*)(out + (size_t)dr * Tdim + c8) = v;
    }
}

// ---------- flash attention: LDS-staged K/V (gload_lds, dbuf), XCD affinity ----------
#define QB 64
#define KB 32
#define PLD 40   // Ps row stride

__device__ __forceinline__ void stage_tile(const unsigned short* Khp, const unsigned short* Klp,
                                           const unsigned short* Vhp, const unsigned short* Vlp,
                                           unsigned short* Kbh, unsigned short* Kbl,
                                           unsigned short* Vbh, unsigned short* Vbl,
                                           int j0, int wid, int lane) {
#pragma unroll
    for (int i2 = 0; i2 < 2; ++i2) {
        int s = (wid * 2 + i2) * 64 + lane;
        int r = s >> 4, ch = (s & 15) ^ (r & 7);
        GL16(Khp + (size_t)(j0 + r) * Cdim + ch * 8, Kbh + s * 8);
        GL16(Klp + (size_t)(j0 + r) * Cdim + ch * 8, Kbl + s * 8);
        int d = s >> 2, cv = (s & 3) ^ ((d >> 1) & 3);
        GL16(Vhp + (size_t)d * Tdim + j0 + cv * 8, Vbh + s * 8);
        GL16(Vlp + (size_t)d * Tdim + j0 + cv * 8, Vbl + s * 8);
    }
}

__global__ __launch_bounds__(256, 2) void attn_k(const unsigned short* __restrict__ Qh,
                                                 const unsigned short* __restrict__ Ql,
                                                 const unsigned short* __restrict__ Kh,
                                                 const unsigned short* __restrict__ Kl,
                                                 const unsigned short* __restrict__ Vth,
                                                 const unsigned short* __restrict__ Vtl,
                                                 unsigned short* __restrict__ ctxq,
                                                 float* __restrict__ Sc) {
    __shared__ unsigned short Kbh[2][4096], Kbl[2][4096];
    __shared__ unsigned short Vbh[2][4096], Vbl[2][4096];
    __shared__ unsigned short Psh[4][16 * PLD], Psl[4][16 * PLD];

    int tid = threadIdx.x, lane = tid & 63, wid = tid >> 6;
    int g = blockIdx.x;
    int xcd = g & 7, sl = g >> 3;
    int combo = xcd + 8 * (sl >> 4);     // 0..31
    int pr = sl & 15;
    int b = combo >> 4, h = combo & 15;

    const size_t qkbase = (size_t)b * Tdim * Cdim + (size_t)h * Dh;
    const size_t vbase  = ((size_t)b * Hn + h) * (size_t)Dh * Tdim;
    const unsigned short* Qhp = Qh + qkbase;
    const unsigned short* Qlp = Ql + qkbase;
    const unsigned short* Khp = Kh + qkbase;
    const unsigned short* Klp = Kl + qkbase;
    const unsigned short* Vhp = Vth + vbase;
    const unsigned short* Vlp = Vtl + vbase;

    int cl = lane & 15;
    int gq = lane >> 4;
    int fk = gq * 8;
    int rb4 = gq * 4;
    const float qscl2 = 0.088388347648318447f * 1.4426950408889634f;  // /sqrt(128) * log2e

    for (int pass = 0; pass < 2; ++pass) {
        int qt = pass ? (31 - pr) : pr;
        int qrow_lo = qt * QB + wid * 16;
        int myrow = qrow_lo + cl;
        int qmax_w = qrow_lo + 15;

        s16x8 qfh[4], qfl[4];
#pragma unroll
        for (int c = 0; c < 4; ++c) {
            qfh[c] = *(const s16x8*)(const void*)(Qhp + (size_t)myrow * Cdim + c * 32 + fk);
            qfl[c] = *(const s16x8*)(const void*)(Qlp + (size_t)myrow * Cdim + c * 32 + fk);
        }

        f32x4 acc[8];
#pragma unroll
        for (int n = 0; n < 8; ++n) acc[n] = (f32x4){0.f, 0.f, 0.f, 0.f};
        float mrun[4], lrun[4];
#pragma unroll
        for (int r = 0; r < 4; ++r) { mrun[r] = -__builtin_inff(); lrun[r] = 0.f; }

        int ntile = 2 * qt + 2;
        int cur = 0;

        stage_tile(Khp, Klp, Vhp, Vlp, Kbh[0], Kbl[0], Vbh[0], Vbl[0], 0, wid, lane);
        __syncthreads();

        for (int t = 0; t < ntile; ++t) {
            int j0 = t * KB;
            if (t + 1 < ntile)
                stage_tile(Khp, Klp, Vhp, Vlp, Kbh[cur ^ 1], Kbl[cur ^ 1],
                           Vbh[cur ^ 1], Vbl[cur ^ 1], j0 + KB, wid, lane);
            if (j0 <= qmax_w) {
                const unsigned short* kbh = Kbh[cur];
                const unsigned short* kbl = Kbl[cur];
                const unsigned short* vbh = Vbh[cur];
                const unsigned short* vbl = Vbl[cur];
                // ---- QK^T from LDS ----
                f32x4 sf[2];
#pragma unroll
                for (int st = 0; st < 2; ++st) {
                    int rr = st * 16 + cl;
                    f32x4 sa = (f32x4){0.f, 0.f, 0.f, 0.f};
#pragma unroll
                    for (int c = 0; c < 4; ++c) {
                        int slot = rr * 16 + ((c * 4 + gq) ^ (rr & 7));
                        s16x8 kfh = *(const s16x8*)(const void*)(kbh + slot * 8);
                        s16x8 kfl = *(const s16x8*)(const void*)(kbl + slot * 8);
                        sa = __builtin_amdgcn_mfma_f32_16x16x32_bf16(qfh[c], kfh, sa, 0, 0, 0);
                        sa = __builtin_amdgcn_mfma_f32_16x16x32_bf16(qfh[c], kfl, sa, 0, 0, 0);
                        sa = __builtin_amdgcn_mfma_f32_16x16x32_bf16(qfl[c], kfh, sa, 0, 0, 0);
                    }
                    sf[st] = sa;
                }
                // ---- log2-scale + causal mask ----
#pragma unroll
                for (int st = 0; st < 2; ++st) {
                    int key = j0 + st * 16 + cl;
#pragma unroll
                    for (int r = 0; r < 4; ++r) {
                        int qr = qrow_lo + rb4 + r;
                        float sv = sf[st][r] * qscl2;
                        sf[st][r] = (key <= qr) ? sv : -__builtin_inff();
                    }
                }
                // ---- online softmax (log2 domain) with defer-max ----
                float tm[4];
                bool need = false;
#pragma unroll
                for (int r = 0; r < 4; ++r) {
                    float t2 = fmaxf(sf[0][r], sf[1][r]);
#pragma unroll
                    for (int o = 8; o; o >>= 1) t2 = fmaxf(t2, __shfl_xor(t2, o));
                    tm[r] = t2;
                    need = need || (t2 > mrun[r] + 8.f);
                }
                if (__any(need)) {
                    float corr[4];
#pragma unroll
                    for (int r = 0; r < 4; ++r) {
                        float mn = fmaxf(mrun[r], tm[r]);
                        corr[r] = exp2_fast(mrun[r] - mn);
                        mrun[r] = mn;
                        lrun[r] *= corr[r];
                    }
#pragma unroll
                    for (int n = 0; n < 8; ++n)
#pragma unroll
                        for (int r = 0; r < 4; ++r) acc[n][r] *= corr[r];
                }
                float p0[4], p1[4];
#pragma unroll
                for (int r = 0; r < 4; ++r) {
                    p0[r] = exp2_fast(sf[0][r] - mrun[r]);
                    p1[r] = exp2_fast(sf[1][r] - mrun[r]);
                    float rs = p0[r] + p1[r];
#pragma unroll
                    for (int o = 8; o; o >>= 1) rs += __shfl_xor(rs, o);
                    lrun[r] += rs;
                }
                // ---- P bounce through per-wave LDS ----
                unsigned short* psh = &Psh[wid][0];
                unsigned short* psl = &Psl[wid][0];
#pragma unroll
                for (int r = 0; r < 4; ++r) {
                    unsigned short h0 = f2bf(p0[r]);
                    unsigned short h1 = f2bf(p1[r]);
                    psh[(rb4 + r) * PLD + cl]      = h0;
                    psl[(rb4 + r) * PLD + cl]      = f2bf(p0[r] - bf2f(h0));
                    psh[(rb4 + r) * PLD + 16 + cl] = h1;
                    psl[(rb4 + r) * PLD + 16 + cl] = f2bf(p1[r] - bf2f(h1));
                }
                s16x8 pfh = *(const s16x8*)(const void*)(psh + cl * PLD + fk);
                s16x8 pfl = *(const s16x8*)(const void*)(psl + cl * PLD + fk);
                // ---- PV from LDS ----
#pragma unroll
                for (int n = 0; n < 8; ++n) {
                    int d = n * 16 + cl;
                    int slot = d * 4 + (gq ^ ((d >> 1) & 3));
                    s16x8 vfh = *(const s16x8*)(const void*)(vbh + slot * 8);
                    s16x8 vfl = *(const s16x8*)(const void*)(vbl + slot * 8);
                    acc[n] = __builtin_amdgcn_mfma_f32_16x16x32_bf16(pfh, vfh, acc[n], 0, 0, 0);
                    acc[n] = __builtin_amdgcn_mfma_f32_16x16x32_bf16(pfh, vfl, acc[n], 0, 0, 0);
                    acc[n] = __builtin_amdgcn_mfma_f32_16x16x32_bf16(pfl, vfh, acc[n], 0, 0, 0);
                }
            }
            __syncthreads();
            cur ^= 1;
        }
        // ---- epilogue: normalize + fused e5m2 block quant ----
        unsigned short* cq = ctxq + qkbase;
#pragma unroll
        for (int r = 0; r < 4; ++r) {
            int trow = qrow_lo + rb4 + r;
            float inv = 1.0f / lrun[r];
            float vals[8];
            float am = 0.f;
#pragma unroll
            for (int n = 0; n < 8; ++n) {
                vals[n] = acc[n][r] * inv;
                am = fmaxf(am, fabsf(vals[n]));
            }
#pragma unroll
            for (int o = 8; o; o >>= 1) am = fmaxf(am, __shfl_xor(am, o));
            float s = fmaxf(am / 57344.0f, 1e-12f);
#pragma unroll
            for (int n = 0; n < 8; ++n)
                cq[(size_t)trow * Cdim + n * 16 + cl] = f2bf(q8_e5m2(vals[n] / s));
            if (cl == 0) Sc[((size_t)b * Tdim + trow) * NKB + h] = s;
        }
    }
}

// ---------- launch ----------
extern "C" void kernel_launch(void* const* d_in, const int* in_sizes, int n_in,
                              void* d_out, int out_size, void* d_ws, size_t ws_size,
                              hipStream_t stream) {
    const float* x  = (const float*)d_in[0];
    const float* wq = (const float*)d_in[2];
    const float* wk = (const float*)d_in[3];
    const float* wv = (const float*)d_in[4];
    const float* wo = (const float*)d_in[5];
    const float* sq = (const float*)d_in[6];
    const float* sk = (const float*)d_in[7];
    const float* sv = (const float*)d_in[8];
    const float* so = (const float*)d_in[9];

    const size_t MB = 1ull << 20;
    char* ws = (char*)d_ws;
    unsigned short* xq  = (unsigned short*)(ws);                       // 0..16: xq -> vth
    unsigned short* vth = (unsigned short*)(ws);
    float*          Sx  = (float*)(ws + 16 * MB);
    float*          Scx = (float*)(ws + (16 * MB + 256 * 1024));
    unsigned short* wdq = (unsigned short*)(ws + (16 * MB + 512 * 1024));
    unsigned short* qh  = (unsigned short*)(ws + (24 * MB + 512 * 1024));
    unsigned short* ql  = (unsigned short*)(ws + (40 * MB + 512 * 1024));
    unsigned short* kh  = (unsigned short*)(ws + (56 * MB + 512 * 1024));
    unsigned short* kl  = (unsigned short*)(ws + (72 * MB + 512 * 1024));
    unsigned short* vh  = (unsigned short*)(ws + (88 * MB + 512 * 1024));  // vh -> vtl
    unsigned short* vtl = (unsigned short*)(ws + (88 * MB + 512 * 1024));
    unsigned short* vl  = (unsigned short*)(ws + (104 * MB + 512 * 1024)); // vl -> cq
    unsigned short* cq  = (unsigned short*)(ws + (104 * MB + 512 * 1024));

    const int n128 = Bdim * Tdim * Cdim / 128;  // 65536
    const int wn = Cdim * Cdim;
    const int Mr = Bdim * Tdim;

    act_quant_q8_k<<<n128 / 4, 256, 0, stream>>>(x, xq, Sx, n128);

    dim3 gg(Cdim / 128, Mr / 128);
    w_quant_k<<<wn / 1024, 256, 0, stream>>>(wq, wdq, wn);
    gemm_k<0><<<gg, 256, 0, stream>>>(xq, Sx, wdq, sq, qh, ql, nullptr, Mr, Cdim, Cdim);
    w_quant_k<<<wn / 1024, 256, 0, stream>>>(wk, wdq, wn);
    gemm_k<0><<<gg, 256, 0, stream>>>(xq, Sx, wdq, sk, kh, kl, nullptr, Mr, Cdim, Cdim);
    w_quant_k<<<wn / 1024, 256, 0, stream>>>(wv, wdq, wn);
    gemm_k<0><<<gg, 256, 0, stream>>>(xq, Sx, wdq, sv, vh, vl, nullptr, Mr, Cdim, Cdim);

    dim3 tg(Tdim / 64, Dh / 64, Bdim * Hn);
    vtrans_k<<<tg, 256, 0, stream>>>(vh, vth);
    vtrans_k<<<tg, 256, 0, stream>>>(vl, vtl);

    attn_k<<<512, 256, 0, stream>>>(qh, ql, kh, kl, vth, vtl, cq, Scx);

    w_quant_k<<<wn / 1024, 256, 0, stream>>>(wo, wdq, wn);
    gemm_k<1><<<gg, 256, 0, stream>>>(cq, Scx, wdq, so, nullptr, nullptr, (float*)d_out, Mr, Cdim, Cdim);
}